// Round 1
// baseline (428.090 us; speedup 1.0000x reference)
//
#include <hip/hip_runtime.h>
#include <math.h>

// Problem constants
#define B 2
#define N 8192
#define M 8192
#define NPTS (B*N)              // 16384 query/target points per cloud set
#define VD 64
#define VH 128
#define VW 128
#define VVOX (VD*VH*VW)         // 1048576 voxels per batch
#define DHH 512
#define DWW 512
#define DPIX (DHH*DWW)          // 262144 pixels per batch

// Workspace layout (float indices)
#define OFF_PACK_P 0                       // NPTS float4 (x,y,z,|p|^2)
#define OFF_PACK_G (NPTS*4)                // NPTS float4 (x,y,z,|g|^2)
#define OFF_MIN_P  (NPTS*8)                // NPTS floats: min over gt for each pred pt
#define OFF_MIN_G  (NPTS*8 + NPTS)         // NPTS floats: min over pred for each gt pt
#define OFF_ACC    (NPTS*8 + 2*NPTS)       // 16 accumulators
// acc: [0,1]=inter_b  [2,3]=psum_b  [4,5]=gsum_b  [6,7]=sum_g_b  [8,9]=sum_g2_b
//      [10]=gradx  [11]=grady  [12]=mask_num  [13]=mask_den

__device__ __forceinline__ float blockSum(float v, volatile float* sm) {
    #pragma unroll
    for (int o = 32; o > 0; o >>= 1) v += __shfl_down(v, o, 64);
    int lane = threadIdx.x & 63, wid = threadIdx.x >> 6;
    __syncthreads();                 // protect sm from previous call's readers
    if (lane == 0) sm[wid] = v;
    __syncthreads();
    return sm[0] + sm[1] + sm[2] + sm[3];
}

// ---- init: min arrays = +inf, accumulators = 0 (ws is poisoned 0xAA each call)
__global__ __launch_bounds__(256) void k_init(float* ws) {
    int i = blockIdx.x * 256 + threadIdx.x;
    if (i < 2*NPTS) ((unsigned int*)(ws + OFF_MIN_P))[i] = 0x7F800000u; // +inf
    if (i < 16) ws[OFF_ACC + i] = 0.f;
}

// ---- pack points as (x,y,z,|.|^2) float4 for scalar-load-friendly inner loop
__global__ __launch_bounds__(256) void k_pack(const float* __restrict__ pc,
                                              const float* __restrict__ gp,
                                              float* ws) {
    int i = blockIdx.x * 256 + threadIdx.x;
    if (i >= NPTS) return;
    float x = pc[3*i], y = pc[3*i+1], z = pc[3*i+2];
    ((float4*)(ws + OFF_PACK_P))[i] = make_float4(x, y, z, x*x + y*y + z*z);
    x = gp[3*i]; y = gp[3*i+1]; z = gp[3*i+2];
    ((float4*)(ws + OFF_PACK_G))[i] = make_float4(x, y, z, x*x + y*y + z*z);
}

// ---- chamfer: 512 blocks = 2 dirs x 4 segments x 64 query-chunks
#define SEG 4
#define SEGLEN (M/SEG)   // 2048
__global__ __launch_bounds__(256) void k_chamfer(float* ws) {
    const float4* packP = (const float4*)(ws + OFF_PACK_P);
    const float4* packG = (const float4*)(ws + OFF_PACK_G);
    unsigned int bid = blockIdx.x;
    int dir  = bid >> 8;        // 0: pred->gt, 1: gt->pred
    int rem  = bid & 255;
    int seg  = rem >> 6;
    int qblk = rem & 63;
    const float4* Q = dir ? packG : packP;
    const float4* T = dir ? packP : packG;
    unsigned int* minArr = (unsigned int*)(ws + (dir ? OFF_MIN_G : OFF_MIN_P));

    int q = qblk * 256 + threadIdx.x;   // [0, 16384)
    int b = q >> 13;                    // batch
    float4 qv = Q[q];
    float nx = -2.f*qv.x, ny = -2.f*qv.y, nz = -2.f*qv.z;
    const float4* t = T + (b*M + seg*SEGLEN);   // wave-uniform base
    float dmin = INFINITY;
    #pragma unroll 8
    for (int j = 0; j < SEGLEN; ++j) {
        float4 tv = t[j];   // uniform index -> s_load_dwordx4
        float d = fmaf(tv.x, nx, fmaf(tv.y, ny, fmaf(tv.z, nz, tv.w)));
        dmin = fminf(dmin, d);
    }
    dmin += qv.w;           // + |q|^2 (constant under the min)
    atomicMin(minArr + q, __float_as_uint(dmin));   // all d >= 0
}

// ---- clDice: erode(sigmoid(x)) == sigmoid(erode(x)) since sigmoid monotone.
// 1024 blocks (512/batch), 2048 voxels/block, 8/thread.
__global__ __launch_bounds__(256) void k_cldice(const float* __restrict__ pv,
                                                const float* __restrict__ gv,
                                                float* ws) {
    __shared__ float sm[4];
    int b = blockIdx.x >> 9;
    int chunk = (blockIdx.x & 511) * 2048;
    const float* pb = pv + b * VVOX;
    const float* gb = gv + b * VVOX;
    float li = 0.f, lp = 0.f, lg = 0.f;
    #pragma unroll
    for (int k = 0; k < 8; ++k) {
        int v = chunk + k*256 + threadIdx.x;
        int w = v & (VW-1);
        int h = (v >> 7) & (VH-1);
        int d = v >> 14;
        int d0 = max(d-1, 0), d1 = min(d+1, VD-1);
        int h0 = max(h-1, 0), h1 = min(h+1, VH-1);
        int w0 = max(w-1, 0), w1 = min(w+1, VW-1);
        float mp = INFINITY, mg = INFINITY;
        for (int dd = d0; dd <= d1; ++dd)
            for (int hh = h0; hh <= h1; ++hh) {
                int base = (dd << 14) + (hh << 7);
                for (int wi = w0; wi <= w1; ++wi) {
                    mp = fminf(mp, pb[base + wi]);
                    mg = fminf(mg, gb[base + wi]);
                }
            }
        float ps = 1.f / (1.f + __expf(-mp));   // sigmoid(erode(pred))
        li += ps * mg; lp += ps; lg += mg;
    }
    float a;
    float* acc = ws + OFF_ACC;
    a = blockSum(li, sm); if (threadIdx.x == 0) atomicAdd(acc + 0 + b, a);
    a = blockSum(lp, sm); if (threadIdx.x == 0) atomicAdd(acc + 2 + b, a);
    a = blockSum(lg, sm); if (threadIdx.x == 0) atomicAdd(acc + 4 + b, a);
}

// ---- depth loss partials: 512 blocks (256/batch), 1024 px/block, 4/thread
__global__ __launch_bounds__(256) void k_depth(const float* __restrict__ pd,
                                               const float* __restrict__ gd,
                                               const float* __restrict__ mk,
                                               float* ws) {
    __shared__ float sm[4];
    int b = blockIdx.x >> 8;
    int chunk = (blockIdx.x & 255) * 1024;
    const float* pb = pd + b * DPIX;
    const float* gb = gd + b * DPIX;
    const float* mb = mk + b * DPIX;
    float sg = 0, sg2 = 0, gx = 0, gy = 0, num = 0, den = 0;
    #pragma unroll
    for (int k = 0; k < 4; ++k) {
        int idx = chunk + k*256 + threadIdx.x;
        int h = idx >> 9;
        int w = idx & 511;
        float p = pb[idx], g = gb[idx], m = mb[idx];
        float lgv = logf(p + 0.1f) - logf(g + 0.1f);
        sg += lgv; sg2 += lgv * lgv;
        if (h < DHH - 1) {
            float p2 = pb[idx + DWW], g2 = gb[idx + DWW];
            gx += fabsf(fabsf(p - p2) - fabsf(g - g2));
        }
        if (w < DWW - 1) {
            float p2 = pb[idx + 1], g2 = gb[idx + 1];
            gy += fabsf(fabsf(p - p2) - fabsf(g - g2));
        }
        num += fabsf(p - g) * m;
        den += m;
    }
    float a;
    float* acc = ws + OFF_ACC;
    a = blockSum(sg,  sm); if (threadIdx.x == 0) atomicAdd(acc + 6 + b, a);
    a = blockSum(sg2, sm); if (threadIdx.x == 0) atomicAdd(acc + 8 + b, a);
    a = blockSum(gx,  sm); if (threadIdx.x == 0) atomicAdd(acc + 10, a);
    a = blockSum(gy,  sm); if (threadIdx.x == 0) atomicAdd(acc + 11, a);
    a = blockSum(num, sm); if (threadIdx.x == 0) atomicAdd(acc + 12, a);
    a = blockSum(den, sm); if (threadIdx.x == 0) atomicAdd(acc + 13, a);
}

// ---- finalize: reduce min arrays, combine all terms, write scalar
__global__ __launch_bounds__(256) void k_final(const float* ws, const int* iter,
                                               float* out) {
    __shared__ float sm[4];
    const float* minP = ws + OFF_MIN_P;
    const float* minG = ws + OFF_MIN_G;
    float s1 = 0.f, s2 = 0.f;
    for (int i = threadIdx.x; i < NPTS; i += 256) { s1 += minP[i]; s2 += minG[i]; }
    s1 = blockSum(s1, sm);
    s2 = blockSum(s2, sm);
    if (threadIdx.x == 0) {
        const float* acc = ws + OFF_ACC;
        float chamfer = s1 / (float)NPTS + s2 / (float)NPTS;
        float dsum = 0.f;
        for (int b = 0; b < 2; ++b)
            dsum += (2.f * acc[0+b] + 1e-5f) / (acc[2+b] + acc[4+b] + 1e-5f);
        float cldice = 1.f - 0.5f * dsum;
        float silog = 0.f;
        for (int b = 0; b < 2; ++b) {
            float gm = acc[6+b] / (float)DPIX;
            float gv = acc[8+b] / (float)DPIX - gm * gm;   // biased var
            silog += 10.f * 0.5f * gv + 10.f * 0.5f * gm * gm;
        }
        float grad_l1 = acc[10] / (float)(B*(DHH-1)*DWW)
                      + acc[11] / (float)(B*DHH*(DWW-1));
        float mask_l1 = acc[12] / (acc[13] + 1e-8f);
        float dloss = silog + grad_l1 + mask_l1;
        int it = iter[0]; if (it < 1) it = 1;
        float gamma1 = 2.f * logf((float)it / 20000.f);
        out[0] = gamma1 * chamfer + 0.5f * cldice + 0.01f * dloss;
    }
}

extern "C" void kernel_launch(void* const* d_in, const int* in_sizes, int n_in,
                              void* d_out, int out_size, void* d_ws, size_t ws_size,
                              hipStream_t stream) {
    const float* pc  = (const float*)d_in[0];   // pred_centers [2,8192,3]
    const float* pv  = (const float*)d_in[1];   // pred_volume  [2,1,64,128,128]
    const float* pd  = (const float*)d_in[2];   // pred_depth   [2,512,512]
    const float* gp  = (const float*)d_in[3];   // gt_points    [2,8192,3]
    const float* gvv = (const float*)d_in[4];   // gt_volume
    const float* gd  = (const float*)d_in[5];   // gt_depth
    const float* mk  = (const float*)d_in[6];   // depth_mask
    const int*   it  = (const int*)d_in[7];     // iteration
    float* ws  = (float*)d_ws;
    float* out = (float*)d_out;

    k_init   <<<128,  256, 0, stream>>>(ws);
    k_pack   <<<64,   256, 0, stream>>>(pc, gp, ws);
    k_chamfer<<<512,  256, 0, stream>>>(ws);
    k_cldice <<<1024, 256, 0, stream>>>(pv, gvv, ws);
    k_depth  <<<512,  256, 0, stream>>>(pd, gd, mk, ws);
    k_final  <<<1,    256, 0, stream>>>(ws, it, out);
}

// Round 2
// 238.022 us; speedup vs baseline: 1.7985x; 1.7985x over previous
//
#include <hip/hip_runtime.h>
#include <math.h>

// Problem constants
#define B 2
#define N 8192
#define M 8192
#define NPTS (B*N)              // 16384 query/target points per cloud set
#define VD 64
#define VH 128
#define VW 128
#define VVOX (VD*VH*VW)         // 1048576 voxels per batch
#define DHH 512
#define DWW 512
#define DPIX (DHH*DWW)          // 262144 pixels per batch

// Workspace layout (float indices)
#define OFF_PACK_P 0                       // NPTS float4 (x,y,z,|p|^2)
#define OFF_PACK_G (NPTS*4)                // NPTS float4 (x,y,z,|g|^2)
#define OFF_MIN_P  (NPTS*8)                // NPTS floats: min over gt for each pred pt
#define OFF_MIN_G  (NPTS*8 + NPTS)         // NPTS floats: min over pred for each gt pt
#define OFF_ACC    (NPTS*8 + 2*NPTS)       // 16 accumulators
// acc: [0,1]=inter_b  [2,3]=psum_b  [4,5]=gsum_b  [6,7]=sum_g_b  [8,9]=sum_g2_b
//      [10]=gradx  [11]=grady  [12]=mask_num  [13]=mask_den

__device__ __forceinline__ float blockSum(float v, volatile float* sm) {
    #pragma unroll
    for (int o = 32; o > 0; o >>= 1) v += __shfl_down(v, o, 64);
    int lane = threadIdx.x & 63, wid = threadIdx.x >> 6;
    __syncthreads();                 // protect sm from previous call's readers
    if (lane == 0) sm[wid] = v;
    __syncthreads();
    return sm[0] + sm[1] + sm[2] + sm[3];
}

// ---- init: min arrays = +inf, accumulators = 0 (ws is poisoned 0xAA each call)
__global__ __launch_bounds__(256) void k_init(float* ws) {
    int i = blockIdx.x * 256 + threadIdx.x;
    if (i < 2*NPTS) ((unsigned int*)(ws + OFF_MIN_P))[i] = 0x7F800000u; // +inf
    if (i < 16) ws[OFF_ACC + i] = 0.f;
}

// ---- pack points as (x,y,z,|.|^2) float4
__global__ __launch_bounds__(256) void k_pack(const float* __restrict__ pc,
                                              const float* __restrict__ gp,
                                              float* ws) {
    int i = blockIdx.x * 256 + threadIdx.x;
    if (i >= NPTS) return;
    float x = pc[3*i], y = pc[3*i+1], z = pc[3*i+2];
    ((float4*)(ws + OFF_PACK_P))[i] = make_float4(x, y, z, x*x + y*y + z*z);
    x = gp[3*i]; y = gp[3*i+1]; z = gp[3*i+2];
    ((float4*)(ws + OFF_PACK_G))[i] = make_float4(x, y, z, x*x + y*y + z*z);
}

// ---- chamfer, register-tiled: 8 queries/thread, targets staged in LDS.
// Per target j: 1 broadcast LDS read amortized over 8x(3 FMA + 1 min) = 32 VALU.
// Grid: 2 dirs x 32 segments x 8 query-blocks = 512 blocks.
#define QT 8
#define SEGS 32
#define TSEG (M/SEGS)   // 256 targets per block, 4KB LDS
__global__ __launch_bounds__(256) void k_chamfer(float* ws) {
    __shared__ float4 tt[TSEG];
    const float4* packP = (const float4*)(ws + OFF_PACK_P);
    const float4* packG = (const float4*)(ws + OFF_PACK_G);
    unsigned int bid = blockIdx.x;
    int dir  = bid >> 8;        // 0: pred->gt, 1: gt->pred
    int rem  = bid & 255;
    int seg  = rem >> 3;        // 0..31
    int qblk = rem & 7;         // 0..7
    const float4* Q = dir ? packG : packP;
    const float4* T = dir ? packP : packG;
    unsigned int* minArr = (unsigned int*)(ws + (dir ? OFF_MIN_G : OFF_MIN_P));

    int qbase = qblk * (256*QT);     // 2048-query chunk; batch-aligned
    int b = qbase >> 13;             // block-uniform batch

    // stage this block's target segment into LDS
    tt[threadIdx.x] = T[b*M + seg*TSEG + threadIdx.x];

    // load 8 query points into registers
    float nx[QT], ny[QT], nz[QT], q2[QT], dmin[QT];
    #pragma unroll
    for (int k = 0; k < QT; ++k) {
        float4 qv = Q[qbase + k*256 + threadIdx.x];
        nx[k] = -2.f*qv.x; ny[k] = -2.f*qv.y; nz[k] = -2.f*qv.z;
        q2[k] = qv.w; dmin[k] = INFINITY;
    }
    __syncthreads();

    #pragma unroll 4
    for (int j = 0; j < TSEG; ++j) {
        float4 tv = tt[j];           // wave-uniform addr -> LDS broadcast
        #pragma unroll
        for (int k = 0; k < QT; ++k) {
            float d = fmaf(tv.x, nx[k], fmaf(tv.y, ny[k], fmaf(tv.z, nz[k], tv.w)));
            dmin[k] = fminf(dmin[k], d);
        }
    }
    #pragma unroll
    for (int k = 0; k < QT; ++k)
        atomicMin(minArr + qbase + k*256 + threadIdx.x,
                  __float_as_uint(dmin[k] + q2[k]));   // d >= 0 (fp noise ~1e-6 ok)
}

// ---- clDice: erode(sigmoid(x)) == sigmoid(erode(x)) since sigmoid monotone.
__global__ __launch_bounds__(256) void k_cldice(const float* __restrict__ pv,
                                                const float* __restrict__ gv,
                                                float* ws) {
    __shared__ float sm[4];
    int b = blockIdx.x >> 9;
    int chunk = (blockIdx.x & 511) * 2048;
    const float* pb = pv + b * VVOX;
    const float* gb = gv + b * VVOX;
    float li = 0.f, lp = 0.f, lg = 0.f;
    #pragma unroll
    for (int k = 0; k < 8; ++k) {
        int v = chunk + k*256 + threadIdx.x;
        int w = v & (VW-1);
        int h = (v >> 7) & (VH-1);
        int d = v >> 14;
        int d0 = max(d-1, 0), d1 = min(d+1, VD-1);
        int h0 = max(h-1, 0), h1 = min(h+1, VH-1);
        int w0 = max(w-1, 0), w1 = min(w+1, VW-1);
        float mp = INFINITY, mg = INFINITY;
        for (int dd = d0; dd <= d1; ++dd)
            for (int hh = h0; hh <= h1; ++hh) {
                int base = (dd << 14) + (hh << 7);
                for (int wi = w0; wi <= w1; ++wi) {
                    mp = fminf(mp, pb[base + wi]);
                    mg = fminf(mg, gb[base + wi]);
                }
            }
        float ps = 1.f / (1.f + __expf(-mp));   // sigmoid(erode(pred))
        li += ps * mg; lp += ps; lg += mg;
    }
    float a;
    float* acc = ws + OFF_ACC;
    a = blockSum(li, sm); if (threadIdx.x == 0) atomicAdd(acc + 0 + b, a);
    a = blockSum(lp, sm); if (threadIdx.x == 0) atomicAdd(acc + 2 + b, a);
    a = blockSum(lg, sm); if (threadIdx.x == 0) atomicAdd(acc + 4 + b, a);
}

// ---- depth loss partials
__global__ __launch_bounds__(256) void k_depth(const float* __restrict__ pd,
                                               const float* __restrict__ gd,
                                               const float* __restrict__ mk,
                                               float* ws) {
    __shared__ float sm[4];
    int b = blockIdx.x >> 8;
    int chunk = (blockIdx.x & 255) * 1024;
    const float* pb = pd + b * DPIX;
    const float* gb = gd + b * DPIX;
    const float* mb = mk + b * DPIX;
    float sg = 0, sg2 = 0, gx = 0, gy = 0, num = 0, den = 0;
    #pragma unroll
    for (int k = 0; k < 4; ++k) {
        int idx = chunk + k*256 + threadIdx.x;
        int h = idx >> 9;
        int w = idx & 511;
        float p = pb[idx], g = gb[idx], m = mb[idx];
        float lgv = logf(p + 0.1f) - logf(g + 0.1f);
        sg += lgv; sg2 += lgv * lgv;
        if (h < DHH - 1) {
            float p2 = pb[idx + DWW], g2 = gb[idx + DWW];
            gx += fabsf(fabsf(p - p2) - fabsf(g - g2));
        }
        if (w < DWW - 1) {
            float p2 = pb[idx + 1], g2 = gb[idx + 1];
            gy += fabsf(fabsf(p - p2) - fabsf(g - g2));
        }
        num += fabsf(p - g) * m;
        den += m;
    }
    float a;
    float* acc = ws + OFF_ACC;
    a = blockSum(sg,  sm); if (threadIdx.x == 0) atomicAdd(acc + 6 + b, a);
    a = blockSum(sg2, sm); if (threadIdx.x == 0) atomicAdd(acc + 8 + b, a);
    a = blockSum(gx,  sm); if (threadIdx.x == 0) atomicAdd(acc + 10, a);
    a = blockSum(gy,  sm); if (threadIdx.x == 0) atomicAdd(acc + 11, a);
    a = blockSum(num, sm); if (threadIdx.x == 0) atomicAdd(acc + 12, a);
    a = blockSum(den, sm); if (threadIdx.x == 0) atomicAdd(acc + 13, a);
}

// ---- finalize: reduce min arrays, combine all terms, write scalar
__global__ __launch_bounds__(256) void k_final(const float* ws, const int* iter,
                                               float* out) {
    __shared__ float sm[4];
    const float* minP = ws + OFF_MIN_P;
    const float* minG = ws + OFF_MIN_G;
    float s1 = 0.f, s2 = 0.f;
    for (int i = threadIdx.x; i < NPTS; i += 256) { s1 += minP[i]; s2 += minG[i]; }
    s1 = blockSum(s1, sm);
    s2 = blockSum(s2, sm);
    if (threadIdx.x == 0) {
        const float* acc = ws + OFF_ACC;
        float chamfer = s1 / (float)NPTS + s2 / (float)NPTS;
        float dsum = 0.f;
        for (int b = 0; b < 2; ++b)
            dsum += (2.f * acc[0+b] + 1e-5f) / (acc[2+b] + acc[4+b] + 1e-5f);
        float cldice = 1.f - 0.5f * dsum;
        float silog = 0.f;
        for (int b = 0; b < 2; ++b) {
            float gm = acc[6+b] / (float)DPIX;
            float gv = acc[8+b] / (float)DPIX - gm * gm;   // biased var
            silog += 10.f * 0.5f * gv + 10.f * 0.5f * gm * gm;
        }
        float grad_l1 = acc[10] / (float)(B*(DHH-1)*DWW)
                      + acc[11] / (float)(B*DHH*(DWW-1));
        float mask_l1 = acc[12] / (acc[13] + 1e-8f);
        float dloss = silog + grad_l1 + mask_l1;
        int it = iter[0]; if (it < 1) it = 1;
        float gamma1 = 2.f * logf((float)it / 20000.f);
        out[0] = gamma1 * chamfer + 0.5f * cldice + 0.01f * dloss;
    }
}

extern "C" void kernel_launch(void* const* d_in, const int* in_sizes, int n_in,
                              void* d_out, int out_size, void* d_ws, size_t ws_size,
                              hipStream_t stream) {
    const float* pc  = (const float*)d_in[0];   // pred_centers [2,8192,3]
    const float* pv  = (const float*)d_in[1];   // pred_volume  [2,1,64,128,128]
    const float* pd  = (const float*)d_in[2];   // pred_depth   [2,512,512]
    const float* gp  = (const float*)d_in[3];   // gt_points    [2,8192,3]
    const float* gvv = (const float*)d_in[4];   // gt_volume
    const float* gd  = (const float*)d_in[5];   // gt_depth
    const float* mk  = (const float*)d_in[6];   // depth_mask
    const int*   it  = (const int*)d_in[7];     // iteration
    float* ws  = (float*)d_ws;
    float* out = (float*)d_out;

    k_init   <<<128,  256, 0, stream>>>(ws);
    k_pack   <<<64,   256, 0, stream>>>(pc, gp, ws);
    k_chamfer<<<512,  256, 0, stream>>>(ws);
    k_cldice <<<1024, 256, 0, stream>>>(pv, gvv, ws);
    k_depth  <<<512,  256, 0, stream>>>(pd, gd, mk, ws);
    k_final  <<<1,    256, 0, stream>>>(ws, it, out);
}